// Round 1
// baseline (189.526 us; speedup 1.0000x reference)
//
#include <hip/hip_runtime.h>
#include <hip/hip_bf16.h>

// ImmuneMemoryModule fused pipeline for MI355X (gfx950).
// Stage 1 (prep):  pack W1/W2/memory into MFMA B-fragment layout [K/8][N][8] bf16,
//                  compute 1/||mem_row||.
// Stage 2 (ff):    xp = query @ B_mat (fp32, memory-bound), ff = [sin,cos] -> bf16
//                  stored [B][32] zero-padded = exact 16x16x32 A-frag layout.
// Stage 3 (fused): h = relu(ff@W1+b1) -> LDS (XOR-swizzled); q = h@W2+b2 -> LDS;
//                  sim-max/argmax via q@memT with per-n 1/|m| scaling (1/|q| is
//                  row-constant positive -> applied once at the end); thresholded
//                  gather of memory rows (fp32 exact) or zeros.

typedef __attribute__((ext_vector_type(8))) short short8;
typedef __attribute__((ext_vector_type(4))) float f32x4;

#define MFMA_BF16(a, b, c) __builtin_amdgcn_mfma_f32_16x16x32_bf16((a), (b), (c), 0, 0, 0)

static __device__ __forceinline__ unsigned short bf16bits(float f) {
  __hip_bfloat16 h = __float2bfloat16(f);
  return __builtin_bit_cast(unsigned short, h);
}

static __device__ __forceinline__ float sel10(const float a[10], int i) {
  float v = a[0];
#pragma unroll
  for (int j = 1; j < 10; ++j) v = (i == j) ? a[j] : v;
  return v;
}

// ---------------------------------------------------------------------------
// prep: blocks 0..15 -> memory-row inverse norms; blocks 16.. -> weight packing
// W1p [4][512][8]  (K=32 zero-padded from 20)
// W2p [64][256][8]
// Mp  [32][1024][8]   Mp[kp][n][j] = memory[n][kp*8+j]
// ---------------------------------------------------------------------------
__global__ __launch_bounds__(256) void prep_kernel(
    const float* __restrict__ W1, const float* __restrict__ W2,
    const float* __restrict__ mem,
    __hip_bfloat16* __restrict__ W1p, __hip_bfloat16* __restrict__ W2p,
    __hip_bfloat16* __restrict__ Mp, float* __restrict__ invmn) {
  const int b = blockIdx.x;
  if (b < 16) {
    const int wv = threadIdx.x >> 6, lane = threadIdx.x & 63;
    for (int i = 0; i < 16; ++i) {
      int row = (b * 4 + wv) * 16 + i;  // 0..1023
      float4 v = ((const float4*)(mem + (size_t)row * 256))[lane];
      float ss = v.x * v.x + v.y * v.y + v.z * v.z + v.w * v.w;
#pragma unroll
      for (int o = 32; o >= 1; o >>= 1) ss += __shfl_xor(ss, o);
      if (lane == 0) invmn[row] = 1.0f / sqrtf(fmaxf(ss, 1e-30f));
    }
  } else {
    const int N1 = 4 * 512 * 8, N2 = 64 * 256 * 8, N3 = 32 * 1024 * 8;
    const int nb = gridDim.x - 16;
    for (int idx = (b - 16) * 256 + threadIdx.x; idx < N1 + N2 + N3; idx += nb * 256) {
      if (idx < N1) {
        int j = idx & 7, n = (idx >> 3) & 511, kp = idx >> 12;
        int k = kp * 8 + j;
        float v = (k < 20) ? W1[k * 512 + n] : 0.0f;
        W1p[idx] = __float2bfloat16(v);
      } else if (idx < N1 + N2) {
        int t = idx - N1;
        int j = t & 7, n = (t >> 3) & 255, kp = t >> 11;
        W2p[t] = __float2bfloat16(W2[(kp * 8 + j) * 256 + n]);
      } else {
        int t = idx - N1 - N2;
        int j = t & 7, n = (t >> 3) & 1023, kp = t >> 13;
        Mp[t] = __float2bfloat16(mem[n * 256 + kp * 8 + j]);
      }
    }
  }
}

// ---------------------------------------------------------------------------
// ff: each 16-lane group handles one row. float4 query loads; B_mat staged in
// LDS as [f][d] (float4 reads are conflict-free + broadcast across groups).
// ff output [B][32] bf16, k=20..31 zeroed.
// ---------------------------------------------------------------------------
__global__ __launch_bounds__(256) void ff_kernel(
    const float* __restrict__ query, const float* __restrict__ Bmat,
    __hip_bfloat16* __restrict__ ff) {
  __shared__ __align__(16) float Bl[10 * 512];  // [f][d], 20 KB
  for (int i = threadIdx.x; i < 5120; i += 256) {
    int d = i / 10, f = i - d * 10;
    Bl[f * 512 + d] = Bmat[i];  // B_mat row-major [512][10]
  }
  __syncthreads();
  const int wv = threadIdx.x >> 6, lane = threadIdx.x & 63;
  const int g = lane >> 4, jj = lane & 15;
  const long row = (long)blockIdx.x * 16 + wv * 4 + g;
  const float4* q4 = (const float4*)(query + row * 512);

  float acc[10];
#pragma unroll
  for (int f = 0; f < 10; ++f) acc[f] = 0.f;
#pragma unroll
  for (int k = 0; k < 8; ++k) {
    float4 qv = q4[jj + 16 * k];
#pragma unroll
    for (int f = 0; f < 10; ++f) {
      float4 bv = *(const float4*)(Bl + f * 512 + 4 * (jj + 16 * k));
      acc[f] = fmaf(qv.x, bv.x, fmaf(qv.y, bv.y, fmaf(qv.z, bv.z, fmaf(qv.w, bv.w, acc[f]))));
    }
  }
#pragma unroll
  for (int f = 0; f < 10; ++f) {
    float s = acc[f];
    s += __shfl_xor(s, 1); s += __shfl_xor(s, 2);
    s += __shfl_xor(s, 4); s += __shfl_xor(s, 8);
    acc[f] = s;
  }
  // lane jj writes packed bf16 pair for k = 2jj, 2jj+1 (same sin/cos decade)
  int base = (jj < 5) ? 2 * jj : 2 * jj - 10;
  float a0 = sel10(acc, base);
  float a1 = sel10(acc, base + 1);
  float v0 = 0.f, v1 = 0.f;
  if (jj < 5) { v0 = sinf(a0); v1 = sinf(a1); }
  else if (jj < 10) { v0 = cosf(a0); v1 = cosf(a1); }
  ushort2 pk;
  pk.x = bf16bits(v0);
  pk.y = bf16bits(v1);
  ((ushort2*)ff)[row * 16 + jj] = pk;
}

// ---------------------------------------------------------------------------
// fused: 64 rows/block, 256 threads (4 waves). All MFMA 16x16x32 bf16.
// ---------------------------------------------------------------------------
__global__ __launch_bounds__(256) void fused_kernel(
    const __hip_bfloat16* __restrict__ ff, const __hip_bfloat16* __restrict__ W1p,
    const float* __restrict__ b1, const __hip_bfloat16* __restrict__ W2p,
    const float* __restrict__ b2, const __hip_bfloat16* __restrict__ Mp,
    const float* __restrict__ invmn, const float* __restrict__ memory,
    float* __restrict__ out) {
  __shared__ __align__(16) char smem[65536 + 1024 + 256 + 1024 + 1024 + 256];
  char* h_base = smem;                                    // 64 KB: h [64][512] bf16 swizzled
  char* q_base = smem;                                    // reused: q [64][256] bf16 swizzled
  float(*qn_part)[64] = (float(*)[64])(smem + 65536);     // [4][64]
  float* invqn = (float*)(smem + 66560);                  // [64]
  float(*redmax)[64] = (float(*)[64])(smem + 66816);      // [4][64]
  int(*redidx)[64] = (int(*)[64])(smem + 67840);          // [4][64]
  int* sel = (int*)(smem + 68864);                        // [64]

  const int tid = threadIdx.x;
  const int w = tid >> 6;
  const int lane = tid & 63;
  const int g = lane >> 4;
  const int jj = lane & 15;
  const long row0 = (long)blockIdx.x * 64;
  const f32x4 zero4 = {0.f, 0.f, 0.f, 0.f};

  // ---- GEMM2: h = relu(ff @ W1 + b1) -> h_lds ----
  short8 a2[4];
#pragma unroll
  for (int rg = 0; rg < 4; ++rg)
    a2[rg] = *(const short8*)(ff + (row0 + rg * 16 + jj) * 32 + g * 8);

#pragma unroll
  for (int ct = 0; ct < 8; ++ct) {
    const int col = (w * 8 + ct) * 16 + jj;
    short8 bfrag = *(const short8*)(W1p + ((size_t)g * 512 + col) * 8);
    float bias = b1[col];
#pragma unroll
    for (int rg = 0; rg < 4; ++rg) {
      f32x4 c = MFMA_BF16(a2[rg], bfrag, zero4);
#pragma unroll
      for (int i = 0; i < 4; ++i) {
        int row = rg * 16 + 4 * g + i;
        float v = c[i] + bias;
        v = v > 0.f ? v : 0.f;
        int boff = row * 1024 + ((col * 2) ^ ((row & 7) << 4));
        *(__hip_bfloat16*)(h_base + boff) = __float2bfloat16(v);
      }
    }
  }
  __syncthreads();

  // ---- GEMM3: q = h @ W2 + b2 (wave w owns q cols [w*64, w*64+64)) ----
  f32x4 acc3[4][4];
#pragma unroll
  for (int rg = 0; rg < 4; ++rg)
#pragma unroll
    for (int ct = 0; ct < 4; ++ct) acc3[rg][ct] = zero4;

  for (int kk = 0; kk < 16; ++kk) {
    short8 af[4], bf[4];
#pragma unroll
    for (int rg = 0; rg < 4; ++rg) {
      int row = rg * 16 + jj;
      int boff = row * 1024 + ((kk * 64 + g * 16) ^ ((row & 7) << 4));
      af[rg] = *(const short8*)(h_base + boff);
    }
#pragma unroll
    for (int ct = 0; ct < 4; ++ct) {
      int col = (w * 4 + ct) * 16 + jj;
      bf[ct] = *(const short8*)(W2p + ((size_t)(kk * 4 + g) * 256 + col) * 8);
    }
#pragma unroll
    for (int rg = 0; rg < 4; ++rg)
#pragma unroll
      for (int ct = 0; ct < 4; ++ct)
        acc3[rg][ct] = MFMA_BF16(af[rg], bf[ct], acc3[rg][ct]);
  }
  __syncthreads();  // all h reads done; LDS becomes q

  float ns[4][4];
#pragma unroll
  for (int rg = 0; rg < 4; ++rg)
#pragma unroll
    for (int i = 0; i < 4; ++i) ns[rg][i] = 0.f;

#pragma unroll
  for (int ct = 0; ct < 4; ++ct) {
    int col = (w * 4 + ct) * 16 + jj;
    float bias = b2[col];
#pragma unroll
    for (int rg = 0; rg < 4; ++rg) {
#pragma unroll
      for (int i = 0; i < 4; ++i) {
        int row = rg * 16 + 4 * g + i;
        float v = acc3[rg][ct][i] + bias;
        ns[rg][i] += v * v;
        int boff = row * 512 + ((col * 2) ^ ((row & 7) << 4));
        *(__hip_bfloat16*)(q_base + boff) = __float2bfloat16(v);
      }
    }
  }
#pragma unroll
  for (int rg = 0; rg < 4; ++rg)
#pragma unroll
    for (int i = 0; i < 4; ++i) {
      float s = ns[rg][i];
      s += __shfl_xor(s, 1); s += __shfl_xor(s, 2);
      s += __shfl_xor(s, 4); s += __shfl_xor(s, 8);
      ns[rg][i] = s;
    }
  if (jj == 0) {
#pragma unroll
    for (int rg = 0; rg < 4; ++rg)
#pragma unroll
      for (int i = 0; i < 4; ++i)
        qn_part[w][rg * 16 + 4 * g + i] = ns[rg][i];
  }
  __syncthreads();
  if (tid < 64) {
    float ss = qn_part[0][tid] + qn_part[1][tid] + qn_part[2][tid] + qn_part[3][tid];
    invqn[tid] = rsqrtf(fmaxf(ss, 1e-30f));
  }

  // ---- GEMM4: running max/argmax of dot * (1/|m_n|) over n ----
  float runmax[4][4];
  int runidx[4][4];
#pragma unroll
  for (int rg = 0; rg < 4; ++rg)
#pragma unroll
    for (int i = 0; i < 4; ++i) { runmax[rg][i] = -1e30f; runidx[rg][i] = 0; }

  float invmn_r[16];
#pragma unroll
  for (int t = 0; t < 16; ++t) invmn_r[t] = invmn[(w * 16 + t) * 16 + jj];

#pragma unroll
  for (int ntc = 0; ntc < 4; ++ntc) {
    f32x4 acc[4][4];
#pragma unroll
    for (int rg = 0; rg < 4; ++rg)
#pragma unroll
      for (int nt = 0; nt < 4; ++nt) acc[rg][nt] = zero4;

    for (int kk = 0; kk < 8; ++kk) {
      short8 af[4], bf[4];
#pragma unroll
      for (int rg = 0; rg < 4; ++rg) {
        int row = rg * 16 + jj;
        int boff = row * 512 + ((kk * 64 + g * 16) ^ ((row & 7) << 4));
        af[rg] = *(const short8*)(q_base + boff);
      }
#pragma unroll
      for (int nt = 0; nt < 4; ++nt) {
        int n = (w * 16 + ntc * 4 + nt) * 16 + jj;
        bf[nt] = *(const short8*)(Mp + ((size_t)(kk * 4 + g) * 1024 + n) * 8);
      }
#pragma unroll
      for (int rg = 0; rg < 4; ++rg)
#pragma unroll
        for (int nt = 0; nt < 4; ++nt)
          acc[rg][nt] = MFMA_BF16(af[rg], bf[nt], acc[rg][nt]);
    }
#pragma unroll
    for (int nt = 0; nt < 4; ++nt) {
      float sc = invmn_r[ntc * 4 + nt];
      int n = (w * 16 + ntc * 4 + nt) * 16 + jj;
#pragma unroll
      for (int rg = 0; rg < 4; ++rg)
#pragma unroll
        for (int i = 0; i < 4; ++i) {
          float v = acc[rg][nt][i] * sc;
          if (v > runmax[rg][i]) { runmax[rg][i] = v; runidx[rg][i] = n; }
        }
    }
  }

  // cross-lane (jj) max+argmax reduce; ties -> smaller index (jnp.argmax)
#pragma unroll
  for (int rg = 0; rg < 4; ++rg)
#pragma unroll
    for (int i = 0; i < 4; ++i) {
      float v = runmax[rg][i];
      int ix = runidx[rg][i];
#pragma unroll
      for (int o = 1; o < 16; o <<= 1) {
        float v2 = __shfl_xor(v, o);
        int i2 = __shfl_xor(ix, o);
        if (v2 > v || (v2 == v && i2 < ix)) { v = v2; ix = i2; }
      }
      runmax[rg][i] = v;
      runidx[rg][i] = ix;
    }
  if (jj == 0) {
#pragma unroll
    for (int rg = 0; rg < 4; ++rg)
#pragma unroll
      for (int i = 0; i < 4; ++i) {
        redmax[w][rg * 16 + 4 * g + i] = runmax[rg][i];
        redidx[w][rg * 16 + 4 * g + i] = runidx[rg][i];
      }
  }
  __syncthreads();

  if (tid < 64) {
    float best = redmax[0][tid];
    int bi = redidx[0][tid];
#pragma unroll
    for (int ww = 1; ww < 4; ++ww) {
      float v = redmax[ww][tid];
      if (v > best) { best = v; bi = redidx[ww][tid]; }  // ties keep earlier w = smaller n
    }
    float ms = best * invqn[tid];
    sel[tid] = (ms < 0.7f) ? -1 : bi;
  }
  __syncthreads();

  // ---- gather / zero write (fp32 exact memory rows) ----
  const float4* mem4 = (const float4*)memory;
  float4* out4 = (float4*)out;
#pragma unroll
  for (int it = 0; it < 16; ++it) {
    int idx = it * 256 + tid;
    int r = idx >> 6, c = idx & 63;
    int s = sel[r];
    float4 v;
    if (s >= 0) v = mem4[(size_t)s * 64 + c];
    else { v.x = 0.f; v.y = 0.f; v.z = 0.f; v.w = 0.f; }
    out4[(row0 + r) * 64 + c] = v;
  }
}

extern "C" void kernel_launch(void* const* d_in, const int* in_sizes, int n_in,
                              void* d_out, int out_size, void* d_ws, size_t ws_size,
                              hipStream_t stream) {
  const float* query = (const float*)d_in[0];
  const float* Bmat = (const float*)d_in[1];
  const float* W1 = (const float*)d_in[2];
  const float* b1 = (const float*)d_in[3];
  const float* W2 = (const float*)d_in[4];
  const float* b2 = (const float*)d_in[5];
  const float* mem = (const float*)d_in[6];
  float* out = (float*)d_out;

  char* ws = (char*)d_ws;
  __hip_bfloat16* ff = (__hip_bfloat16*)ws;                                  // 4 MB
  __hip_bfloat16* W1p = (__hip_bfloat16*)(ws + 4194304);                     // 32 KB
  __hip_bfloat16* W2p = (__hip_bfloat16*)(ws + 4194304 + 32768);             // 256 KB
  __hip_bfloat16* Mp = (__hip_bfloat16*)(ws + 4194304 + 32768 + 262144);     // 512 KB
  float* invmn = (float*)(ws + 4194304 + 32768 + 262144 + 524288);           // 4 KB

  prep_kernel<<<dim3(256), dim3(256), 0, stream>>>(W1, W2, mem, W1p, W2p, Mp, invmn);
  ff_kernel<<<dim3(4096), dim3(256), 0, stream>>>(query, Bmat, ff);
  fused_kernel<<<dim3(1024), dim3(256), 0, stream>>>(ff, W1p, b1, W2p, b2, Mp, invmn, mem, out);
}